// Round 4
// baseline (139.765 us; speedup 1.0000x reference)
//
#include <hip/hip_runtime.h>

// N=4, C=32, H=W=256, KS=3, O=C*9=288
// ws layout: p [4,32,32,32] (131072 f) | y [4,288,32,32] (1179648 f)
#define N_ 4
#define C_ 32
#define H_ 256
#define W_ 256
#define O_ 288
#define PH 32
#define P_ELEMS (N_*C_*PH*PH)
#define Y_ELEMS (N_*O_*PH*PH)
#define OUT_ELEMS (N_*C_*H_*W_)

typedef float v4f __attribute__((ext_vector_type(4)));

// Kernel 1: psf -> 1/4 bilinear (avg of 2x2 at rows/cols {4o+1,4o+2}) -> maxpool2
__global__ __launch_bounds__(256) void k_downsample(
    const float* __restrict__ psf, float* __restrict__ p) {
  int tid = blockIdx.x * blockDim.x + threadIdx.x;
  if (tid >= P_ELEMS) return;
  int tx = tid & 31;
  int ty = (tid >> 5) & 31;
  int nc = tid >> 10;
  const float* x = psf + (size_t)nc * (H_ * W_);
  float m = -1e30f;
#pragma unroll
  for (int a = 0; a < 2; a++) {
#pragma unroll
    for (int b = 0; b < 2; b++) {
      int r0 = 8 * ty + 4 * a + 1;
      int c0 = 8 * tx + 4 * b + 1;
      const float* row0 = x + r0 * W_ + c0;
      const float* row1 = row0 + W_;
      float avg = 0.25f * (row0[0] + row0[1] + row1[0] + row1[1]);
      m = fmaxf(m, avg);
    }
  }
  p[tid] = m;
}

// Kernel 2 (R2 version): one block per (n,o); block-uniform weights (scalar
// loads); each thread computes 4 consecutive hw via float4.
__global__ __launch_bounds__(256) void k_conv1x1(
    const float* __restrict__ p, const float* __restrict__ w1,
    const float* __restrict__ b1, const float* __restrict__ ws,
    const float* __restrict__ bs, float* __restrict__ y) {
  int bid = blockIdx.x;           // n*O_ + o
  int n = bid / O_;
  int o = bid - n * O_;
  const float4* p4 = (const float4*)(p + (size_t)n * (C_ * PH * PH));
  const float* w1o = w1 + o * C_;
  const float* wso = ws + o * C_;
  float bb1 = b1[o];
  float bbs = bs[o];
  int t = threadIdx.x;
  float a1x = bb1, a1y = bb1, a1z = bb1, a1w = bb1;
  float a2x = bbs, a2y = bbs, a2z = bbs, a2w = bbs;
#pragma unroll
  for (int c = 0; c < C_; c++) {
    float4 pv = p4[c * 256 + t];
    float u1 = w1o[c], u2 = wso[c];
    a1x = fmaf(pv.x, u1, a1x); a1y = fmaf(pv.y, u1, a1y);
    a1z = fmaf(pv.z, u1, a1z); a1w = fmaf(pv.w, u1, a1w);
    a2x = fmaf(pv.x, u2, a2x); a2y = fmaf(pv.y, u2, a2y);
    a2z = fmaf(pv.z, u2, a2z); a2w = fmaf(pv.w, u2, a2w);
  }
  float4 r;
  r.x = ((a1x >= 0.f) ? a1x : 0.2f * a1x) + a2x;
  r.y = ((a1y >= 0.f) ? a1y : 0.2f * a1y) + a2y;
  r.z = ((a1z >= 0.f) ? a1z : 0.2f * a1z) + a2z;
  r.w = ((a1w >= 0.f) ? a1w : 0.2f * a1w) + a2w;
  ((float4*)(y + (size_t)bid * (PH * PH)))[t] = r;
}

// Kernel 3: fused x8 bilinear upsample + per-pixel 3x3 dynamic filter.
// 16 outputs/thread along w (w = 16m+j, j=0..15). Source cols per group:
// {2m-1, 2m, 2m+1, 2m+2} (clamped; clamps make d=0 so borders are exact).
//   j=0..3 : yv = tb0 + (0.5625+0.125j)     * (tb1-tb0)
//   j=4..11: yv = tb1 + (0.0625+0.125(j-4)) * (tb2-tb1)
//   j=12..15:yv = tb2 + (0.0625+0.125(j-12))* (tb3-tb2)
__global__ __launch_bounds__(256) void k_fac(
    const float* __restrict__ fm, const float* __restrict__ y,
    float* __restrict__ out) {
  int bid = blockIdx.x;                     // 2048 blocks
  int work = (bid >> 3) + (bid & 7) * 256;  // XCD-contiguous plane ranges
  int g = (work << 8) + threadIdx.x;        // 524288 threads, 16 out each
  int m = g & 15;
  int h = (g >> 4) & 255;
  int c = (g >> 12) & 31;
  int n = g >> 17;

  float sh = fmaxf(0.125f * (float)h - 0.4375f, 0.f);
  int y0 = (int)sh;
  float wy = sh - (float)y0;
  int y1 = min(y0 + 1, 31);
  int ro0 = y0 << 5, ro1 = y1 << 5;

  int c0 = max(2 * m - 1, 0);
  int c1 = 2 * m;
  int c2 = 2 * m + 1;
  int c3 = min(2 * m + 2, 31);

  const float* yb = y + ((size_t)(n * O_ + c * 9) << 10);
  const float* fb = fm + ((size_t)(n * C_ + c) << 16);

  float acc[16];
#pragma unroll
  for (int j = 0; j < 16; j++) acc[j] = 0.f;

#pragma unroll
  for (int ky = 0; ky < 3; ky++) {
    int row = h + ky - 1;
    float fv[18];
    if (row >= 0 && row < 256) {
      const float* fr = fb + (row << 8) + (m << 4);
      v4f q0 = *(const v4f*)(fr);
      v4f q1 = *(const v4f*)(fr + 4);
      v4f q2 = *(const v4f*)(fr + 8);
      v4f q3 = *(const v4f*)(fr + 12);
      fv[0] = (m > 0) ? fr[-1] : 0.f;
      fv[1] = q0.x;  fv[2] = q0.y;  fv[3] = q0.z;  fv[4] = q0.w;
      fv[5] = q1.x;  fv[6] = q1.y;  fv[7] = q1.z;  fv[8] = q1.w;
      fv[9] = q2.x;  fv[10] = q2.y; fv[11] = q2.z; fv[12] = q2.w;
      fv[13] = q3.x; fv[14] = q3.y; fv[15] = q3.z; fv[16] = q3.w;
      fv[17] = (m < 15) ? fr[16] : 0.f;
    } else {
#pragma unroll
      for (int t = 0; t < 18; t++) fv[t] = 0.f;
    }
#pragma unroll
    for (int kx = 0; kx < 3; kx++) {
      const float* yp = yb + ((3 * ky + kx) << 10);
      float t0 = yp[ro0 + c0], t1 = yp[ro0 + c1];
      float t2 = yp[ro0 + c2], t3 = yp[ro0 + c3];
      float u0 = yp[ro1 + c0], u1 = yp[ro1 + c1];
      float u2 = yp[ro1 + c2], u3 = yp[ro1 + c3];
      float tb0 = fmaf(wy, u0 - t0, t0);
      float tb1 = fmaf(wy, u1 - t1, t1);
      float tb2 = fmaf(wy, u2 - t2, t2);
      float tb3 = fmaf(wy, u3 - t3, t3);
      float d0 = tb1 - tb0;
      float d1 = tb2 - tb1;
      float d2 = tb3 - tb2;
      acc[0]  = fmaf(fv[0 + kx],  fmaf(0.5625f, d0, tb0), acc[0]);
      acc[1]  = fmaf(fv[1 + kx],  fmaf(0.6875f, d0, tb0), acc[1]);
      acc[2]  = fmaf(fv[2 + kx],  fmaf(0.8125f, d0, tb0), acc[2]);
      acc[3]  = fmaf(fv[3 + kx],  fmaf(0.9375f, d0, tb0), acc[3]);
      acc[4]  = fmaf(fv[4 + kx],  fmaf(0.0625f, d1, tb1), acc[4]);
      acc[5]  = fmaf(fv[5 + kx],  fmaf(0.1875f, d1, tb1), acc[5]);
      acc[6]  = fmaf(fv[6 + kx],  fmaf(0.3125f, d1, tb1), acc[6]);
      acc[7]  = fmaf(fv[7 + kx],  fmaf(0.4375f, d1, tb1), acc[7]);
      acc[8]  = fmaf(fv[8 + kx],  fmaf(0.5625f, d1, tb1), acc[8]);
      acc[9]  = fmaf(fv[9 + kx],  fmaf(0.6875f, d1, tb1), acc[9]);
      acc[10] = fmaf(fv[10 + kx], fmaf(0.8125f, d1, tb1), acc[10]);
      acc[11] = fmaf(fv[11 + kx], fmaf(0.9375f, d1, tb1), acc[11]);
      acc[12] = fmaf(fv[12 + kx], fmaf(0.0625f, d2, tb2), acc[12]);
      acc[13] = fmaf(fv[13 + kx], fmaf(0.1875f, d2, tb2), acc[13]);
      acc[14] = fmaf(fv[14 + kx], fmaf(0.3125f, d2, tb2), acc[14]);
      acc[15] = fmaf(fv[15 + kx], fmaf(0.4375f, d2, tb2), acc[15]);
    }
  }
  float* ob = out + ((size_t)(((n * C_ + c) << 8) + h) << 8) + (m << 4);
  v4f r0 = {acc[0], acc[1], acc[2], acc[3]};
  v4f r1 = {acc[4], acc[5], acc[6], acc[7]};
  v4f r2 = {acc[8], acc[9], acc[10], acc[11]};
  v4f r3 = {acc[12], acc[13], acc[14], acc[15]};
  __builtin_nontemporal_store(r0, (v4f*)ob);
  __builtin_nontemporal_store(r1, (v4f*)(ob + 4));
  __builtin_nontemporal_store(r2, (v4f*)(ob + 8));
  __builtin_nontemporal_store(r3, (v4f*)(ob + 12));
}

extern "C" void kernel_launch(void* const* d_in, const int* in_sizes, int n_in,
                              void* d_out, int out_size, void* d_ws,
                              size_t ws_size, hipStream_t stream) {
  const float* psf = (const float*)d_in[0];
  const float* fm = (const float*)d_in[1];
  const float* w1 = (const float*)d_in[2];
  const float* b1 = (const float*)d_in[3];
  const float* ws = (const float*)d_in[4];
  const float* bs = (const float*)d_in[5];
  float* out = (float*)d_out;

  float* p = (float*)d_ws;
  float* y = p + P_ELEMS;

  k_downsample<<<P_ELEMS / 256, 256, 0, stream>>>(psf, p);
  k_conv1x1<<<N_ * O_, 256, 0, stream>>>(p, w1, b1, ws, bs, y);
  k_fac<<<OUT_ELEMS / (16 * 256), 256, 0, stream>>>(fm, y, out);
}

// Round 5
// 132.724 us; speedup vs baseline: 1.0531x; 1.0531x over previous
//
#include <hip/hip_runtime.h>

// N=4, C=32, H=W=256, KS=3, O=C*9=288
// ws layout: p [4,32,32,32] (131072 f) | y [4,288,32,32] (1179648 f)
#define N_ 4
#define C_ 32
#define H_ 256
#define W_ 256
#define O_ 288
#define PH 32
#define P_ELEMS (N_*C_*PH*PH)
#define Y_ELEMS (N_*O_*PH*PH)
#define OUT_ELEMS (N_*C_*H_*W_)

// Kernel 1: psf -> 1/4 bilinear (avg of 2x2 at rows/cols {4o+1,4o+2}) -> maxpool2
// float4 loads at 16B-aligned base 8tx+4b; the 2x2 avg uses lanes .y/.z.
__global__ __launch_bounds__(256) void k_downsample(
    const float* __restrict__ psf, float* __restrict__ p) {
  int tid = blockIdx.x * blockDim.x + threadIdx.x;
  if (tid >= P_ELEMS) return;
  int tx = tid & 31;
  int ty = (tid >> 5) & 31;
  int nc = tid >> 10;
  const float* x = psf + (size_t)nc * (H_ * W_);
  float m = -1e30f;
#pragma unroll
  for (int a = 0; a < 2; a++) {
#pragma unroll
    for (int b = 0; b < 2; b++) {
      int r0 = 8 * ty + 4 * a + 1;
      int c0 = 8 * tx + 4 * b;          // 16B-aligned base; cols used: c0+1,c0+2
      const float4 q0 = *(const float4*)(x + r0 * W_ + c0);
      const float4 q1 = *(const float4*)(x + (r0 + 1) * W_ + c0);
      float avg = 0.25f * (q0.y + q0.z + q1.y + q1.z);
      m = fmaxf(m, avg);
    }
  }
  p[tid] = m;
}

// Kernel 2: one block per (n,o); block-uniform weights (scalar loads);
// each thread computes 4 consecutive hw via float4.
__global__ __launch_bounds__(256) void k_conv1x1(
    const float* __restrict__ p, const float* __restrict__ w1,
    const float* __restrict__ b1, const float* __restrict__ ws,
    const float* __restrict__ bs, float* __restrict__ y) {
  int bid = blockIdx.x;           // n*O_ + o
  int n = bid / O_;
  int o = bid - n * O_;
  const float4* p4 = (const float4*)(p + (size_t)n * (C_ * PH * PH));
  const float* w1o = w1 + o * C_;
  const float* wso = ws + o * C_;
  float bb1 = b1[o];
  float bbs = bs[o];
  int t = threadIdx.x;
  float a1x = bb1, a1y = bb1, a1z = bb1, a1w = bb1;
  float a2x = bbs, a2y = bbs, a2z = bbs, a2w = bbs;
#pragma unroll
  for (int c = 0; c < C_; c++) {
    float4 pv = p4[c * 256 + t];
    float u1 = w1o[c], u2 = wso[c];
    a1x = fmaf(pv.x, u1, a1x); a1y = fmaf(pv.y, u1, a1y);
    a1z = fmaf(pv.z, u1, a1z); a1w = fmaf(pv.w, u1, a1w);
    a2x = fmaf(pv.x, u2, a2x); a2y = fmaf(pv.y, u2, a2y);
    a2z = fmaf(pv.z, u2, a2z); a2w = fmaf(pv.w, u2, a2w);
  }
  float4 r;
  r.x = ((a1x >= 0.f) ? a1x : 0.2f * a1x) + a2x;
  r.y = ((a1y >= 0.f) ? a1y : 0.2f * a1y) + a2y;
  r.z = ((a1z >= 0.f) ? a1z : 0.2f * a1z) + a2z;
  r.w = ((a1w >= 0.f) ? a1w : 0.2f * a1w) + a2w;
  ((float4*)(y + (size_t)bid * (PH * PH)))[t] = r;
}

// Kernel 3 (R2-proven): fused x8 bilinear upsample + per-pixel 3x3 dynamic
// filter, 8 outputs/thread along w. For w=8m+j:
//   j<4 : lerp cols (m-1, m) with wx=0.5625+0.125j
//   j>=4: lerp cols (m, m+1) with wx=0.0625+0.125(j-4)
// Clamped edge columns give d=0 so the same formula is exact at borders.
__global__ __launch_bounds__(256) void k_fac(
    const float* __restrict__ fm, const float* __restrict__ y,
    float* __restrict__ out) {
  int bid = blockIdx.x;
  int work = (bid >> 3) + (bid & 7) * 512;  // XCD-contiguous plane ranges
  int g = (work << 8) + threadIdx.x;
  int m = g & 31;
  int h = (g >> 5) & 255;
  int c = (g >> 13) & 31;
  int n = g >> 18;

  float sh = fmaxf(0.125f * (float)h - 0.4375f, 0.f);
  int y0 = (int)sh;
  float wy = sh - (float)y0;
  int y1 = min(y0 + 1, 31);
  int cm1 = max(m - 1, 0);
  int cp1 = min(m + 1, 31);
  int ro0 = y0 * 32, ro1 = y1 * 32;

  const float* yb = y + ((size_t)(n * O_ + c * 9) << 10);
  const float* fb = fm + ((size_t)(n * C_ + c) << 16);

  float acc0 = 0.f, acc1 = 0.f, acc2 = 0.f, acc3 = 0.f;
  float acc4 = 0.f, acc5 = 0.f, acc6 = 0.f, acc7 = 0.f;

#pragma unroll
  for (int ky = 0; ky < 3; ky++) {
    int row = h + ky - 1;
    float fv[10];
    if (row >= 0 && row < 256) {
      const float* fr = fb + (row << 8) + (m << 3);
      float4 q0 = *(const float4*)(fr);
      float4 q1 = *(const float4*)(fr + 4);
      fv[0] = (m > 0) ? fr[-1] : 0.f;
      fv[1] = q0.x; fv[2] = q0.y; fv[3] = q0.z; fv[4] = q0.w;
      fv[5] = q1.x; fv[6] = q1.y; fv[7] = q1.z; fv[8] = q1.w;
      fv[9] = (m < 31) ? fr[8] : 0.f;
    } else {
#pragma unroll
      for (int t = 0; t < 10; t++) fv[t] = 0.f;
    }
#pragma unroll
    for (int kx = 0; kx < 3; kx++) {
      const float* yp = yb + ((3 * ky + kx) << 10);
      float t0 = yp[ro0 + cm1], t1 = yp[ro0 + m], t2 = yp[ro0 + cp1];
      float u0 = yp[ro1 + cm1], u1 = yp[ro1 + m], u2 = yp[ro1 + cp1];
      float tb0 = fmaf(wy, u0 - t0, t0);
      float tb1 = fmaf(wy, u1 - t1, t1);
      float tb2 = fmaf(wy, u2 - t2, t2);
      float d0 = tb1 - tb0;
      float d1 = tb2 - tb1;
      acc0 = fmaf(fv[0 + kx], fmaf(0.5625f, d0, tb0), acc0);
      acc1 = fmaf(fv[1 + kx], fmaf(0.6875f, d0, tb0), acc1);
      acc2 = fmaf(fv[2 + kx], fmaf(0.8125f, d0, tb0), acc2);
      acc3 = fmaf(fv[3 + kx], fmaf(0.9375f, d0, tb0), acc3);
      acc4 = fmaf(fv[4 + kx], fmaf(0.0625f, d1, tb1), acc4);
      acc5 = fmaf(fv[5 + kx], fmaf(0.1875f, d1, tb1), acc5);
      acc6 = fmaf(fv[6 + kx], fmaf(0.3125f, d1, tb1), acc6);
      acc7 = fmaf(fv[7 + kx], fmaf(0.4375f, d1, tb1), acc7);
    }
  }
  float* ob = out + ((size_t)(((n * C_ + c) << 8) + h) << 8) + (m << 3);
  float4 r0 = {acc0, acc1, acc2, acc3};
  float4 r1 = {acc4, acc5, acc6, acc7};
  *(float4*)(ob) = r0;
  *(float4*)(ob + 4) = r1;
}

extern "C" void kernel_launch(void* const* d_in, const int* in_sizes, int n_in,
                              void* d_out, int out_size, void* d_ws,
                              size_t ws_size, hipStream_t stream) {
  const float* psf = (const float*)d_in[0];
  const float* fm = (const float*)d_in[1];
  const float* w1 = (const float*)d_in[2];
  const float* b1 = (const float*)d_in[3];
  const float* ws = (const float*)d_in[4];
  const float* bs = (const float*)d_in[5];
  float* out = (float*)d_out;

  float* p = (float*)d_ws;
  float* y = p + P_ELEMS;

  k_downsample<<<P_ELEMS / 256, 256, 0, stream>>>(psf, p);
  k_conv1x1<<<N_ * O_, 256, 0, stream>>>(p, w1, b1, ws, bs, y);
  k_fac<<<OUT_ELEMS / (8 * 256), 256, 0, stream>>>(fm, y, out);
}

// Round 6
// 129.331 us; speedup vs baseline: 1.0807x; 1.0262x over previous
//
#include <hip/hip_runtime.h>

// N=4, C=32, H=W=256, KS=3, O=C*9=288
// ws layout: p [4,32,32,32] (131072 f) | y [4,288,32,32] (1179648 f)
#define N_ 4
#define C_ 32
#define H_ 256
#define W_ 256
#define O_ 288
#define PH 32
#define P_ELEMS (N_*C_*PH*PH)
#define Y_ELEMS (N_*O_*PH*PH)
#define OUT_ELEMS (N_*C_*H_*W_)

// Kernel 1: psf -> 1/4 bilinear (avg of 2x2 at rows/cols {4o+1,4o+2}) -> maxpool2
__global__ __launch_bounds__(256) void k_downsample(
    const float* __restrict__ psf, float* __restrict__ p) {
  int tid = blockIdx.x * blockDim.x + threadIdx.x;
  if (tid >= P_ELEMS) return;
  int tx = tid & 31;
  int ty = (tid >> 5) & 31;
  int nc = tid >> 10;
  const float* x = psf + (size_t)nc * (H_ * W_);
  float m = -1e30f;
#pragma unroll
  for (int a = 0; a < 2; a++) {
#pragma unroll
    for (int b = 0; b < 2; b++) {
      int r0 = 8 * ty + 4 * a + 1;
      int c0 = 8 * tx + 4 * b;          // 16B-aligned base; cols used: c0+1,c0+2
      const float4 q0 = *(const float4*)(x + r0 * W_ + c0);
      const float4 q1 = *(const float4*)(x + (r0 + 1) * W_ + c0);
      float avg = 0.25f * (q0.y + q0.z + q1.y + q1.z);
      m = fmaxf(m, avg);
    }
  }
  p[tid] = m;
}

// Kernel 2: one block per (n,o); block-uniform weights (scalar loads);
// each thread computes 4 consecutive hw via float4.
__global__ __launch_bounds__(256) void k_conv1x1(
    const float* __restrict__ p, const float* __restrict__ w1,
    const float* __restrict__ b1, const float* __restrict__ ws,
    const float* __restrict__ bs, float* __restrict__ y) {
  int bid = blockIdx.x;           // n*O_ + o
  int n = bid / O_;
  int o = bid - n * O_;
  const float4* p4 = (const float4*)(p + (size_t)n * (C_ * PH * PH));
  const float* w1o = w1 + o * C_;
  const float* wso = ws + o * C_;
  float bb1 = b1[o];
  float bbs = bs[o];
  int t = threadIdx.x;
  float a1x = bb1, a1y = bb1, a1z = bb1, a1w = bb1;
  float a2x = bbs, a2y = bbs, a2z = bbs, a2w = bbs;
#pragma unroll
  for (int c = 0; c < C_; c++) {
    float4 pv = p4[c * 256 + t];
    float u1 = w1o[c], u2 = wso[c];
    a1x = fmaf(pv.x, u1, a1x); a1y = fmaf(pv.y, u1, a1y);
    a1z = fmaf(pv.z, u1, a1z); a1w = fmaf(pv.w, u1, a1w);
    a2x = fmaf(pv.x, u2, a2x); a2y = fmaf(pv.y, u2, a2y);
    a2z = fmaf(pv.z, u2, a2z); a2w = fmaf(pv.w, u2, a2w);
  }
  float4 r;
  r.x = ((a1x >= 0.f) ? a1x : 0.2f * a1x) + a2x;
  r.y = ((a1y >= 0.f) ? a1y : 0.2f * a1y) + a2y;
  r.z = ((a1z >= 0.f) ? a1z : 0.2f * a1z) + a2z;
  r.w = ((a1w >= 0.f) ? a1w : 0.2f * a1w) + a2w;
  ((float4*)(y + (size_t)bid * (PH * PH)))[t] = r;
}

// Kernel 3: fused x8 bilinear upsample + per-pixel 3x3 dynamic filter.
// Block covers one (n,c) plane, h in [8a, 8a+7], all 32 w-groups.
// y needs per block: rows {a-1, a, a+1} (clamped) x 9 taps x 32 cols = 864
// floats -> staged in LDS once, then conflict-free ds_reads (cols stride-1).
// Per thread: 8 outputs along w (w = 8m+j); clamped edges give d=0 (exact).
__global__ __launch_bounds__(256) void k_fac(
    const float* __restrict__ fm, const float* __restrict__ y,
    float* __restrict__ out) {
  __shared__ float ysh[27 * 32];            // [k*3 + rr][cc]
  int bid = blockIdx.x;
  int work = (bid >> 3) + (bid & 7) * 512;  // XCD-contiguous plane ranges
  int a = work & 31;                        // h-group
  int c = (work >> 5) & 31;
  int n = work >> 10;

  const float* yb = y + ((size_t)(n * O_ + c * 9) << 10);
  int rowg[3];
  rowg[0] = max(a - 1, 0);
  rowg[1] = a;
  rowg[2] = min(a + 1, 31);

  int t = threadIdx.x;
#pragma unroll
  for (int i = t; i < 864; i += 256) {
    int j = i >> 5;                         // staged row 0..26
    int cc = i & 31;
    int k = j / 3;
    int rr = j - 3 * k;
    ysh[i] = yb[(k << 10) + (rowg[rr] << 5) + cc];
  }
  __syncthreads();

  int m = t & 31;
  int h = (a << 3) + (t >> 5);
  float sh = fmaxf(0.125f * (float)h - 0.4375f, 0.f);
  int y0 = (int)sh;
  float wy = sh - (float)y0;
  int rsel0 = y0 - (a - 1);                 // 0 or 1 (a=0 edge -> 1)
  int cm1 = max(m - 1, 0);
  int cp1 = min(m + 1, 31);
  int lo0 = (rsel0 << 5);                   // within [k*96 ...]
  int lo1 = lo0 + 32;

  const float* fb = fm + ((size_t)(n * C_ + c) << 16);

  float acc0 = 0.f, acc1 = 0.f, acc2 = 0.f, acc3 = 0.f;
  float acc4 = 0.f, acc5 = 0.f, acc6 = 0.f, acc7 = 0.f;

#pragma unroll
  for (int ky = 0; ky < 3; ky++) {
    int row = h + ky - 1;
    float fv[10];
    if (row >= 0 && row < 256) {
      const float* fr = fb + (row << 8) + (m << 3);
      float4 q0 = *(const float4*)(fr);
      float4 q1 = *(const float4*)(fr + 4);
      fv[0] = (m > 0) ? fr[-1] : 0.f;
      fv[1] = q0.x; fv[2] = q0.y; fv[3] = q0.z; fv[4] = q0.w;
      fv[5] = q1.x; fv[6] = q1.y; fv[7] = q1.z; fv[8] = q1.w;
      fv[9] = (m < 31) ? fr[8] : 0.f;
    } else {
#pragma unroll
      for (int tt = 0; tt < 10; tt++) fv[tt] = 0.f;
    }
#pragma unroll
    for (int kx = 0; kx < 3; kx++) {
      const float* yp = ysh + 96 * (3 * ky + kx);
      float t0 = yp[lo0 + cm1], t1 = yp[lo0 + m], t2 = yp[lo0 + cp1];
      float u0 = yp[lo1 + cm1], u1 = yp[lo1 + m], u2 = yp[lo1 + cp1];
      float tb0 = fmaf(wy, u0 - t0, t0);
      float tb1 = fmaf(wy, u1 - t1, t1);
      float tb2 = fmaf(wy, u2 - t2, t2);
      float d0 = tb1 - tb0;
      float d1 = tb2 - tb1;
      acc0 = fmaf(fv[0 + kx], fmaf(0.5625f, d0, tb0), acc0);
      acc1 = fmaf(fv[1 + kx], fmaf(0.6875f, d0, tb0), acc1);
      acc2 = fmaf(fv[2 + kx], fmaf(0.8125f, d0, tb0), acc2);
      acc3 = fmaf(fv[3 + kx], fmaf(0.9375f, d0, tb0), acc3);
      acc4 = fmaf(fv[4 + kx], fmaf(0.0625f, d1, tb1), acc4);
      acc5 = fmaf(fv[5 + kx], fmaf(0.1875f, d1, tb1), acc5);
      acc6 = fmaf(fv[6 + kx], fmaf(0.3125f, d1, tb1), acc6);
      acc7 = fmaf(fv[7 + kx], fmaf(0.4375f, d1, tb1), acc7);
    }
  }
  float* ob = out + ((size_t)(((n * C_ + c) << 8) + h) << 8) + (m << 3);
  float4 r0 = {acc0, acc1, acc2, acc3};
  float4 r1 = {acc4, acc5, acc6, acc7};
  *(float4*)(ob) = r0;
  *(float4*)(ob + 4) = r1;
}

extern "C" void kernel_launch(void* const* d_in, const int* in_sizes, int n_in,
                              void* d_out, int out_size, void* d_ws,
                              size_t ws_size, hipStream_t stream) {
  const float* psf = (const float*)d_in[0];
  const float* fm = (const float*)d_in[1];
  const float* w1 = (const float*)d_in[2];
  const float* b1 = (const float*)d_in[3];
  const float* ws = (const float*)d_in[4];
  const float* bs = (const float*)d_in[5];
  float* out = (float*)d_out;

  float* p = (float*)d_ws;
  float* y = p + P_ELEMS;

  k_downsample<<<P_ELEMS / 256, 256, 0, stream>>>(psf, p);
  k_conv1x1<<<N_ * O_, 256, 0, stream>>>(p, w1, b1, ws, bs, y);
  k_fac<<<OUT_ELEMS / (8 * 256), 256, 0, stream>>>(fm, y, out);
}